// Round 6
// baseline (465.133 us; speedup 1.0000x reference)
//
#include <hip/hip_runtime.h>

#define B_DIM 16
#define U_DIM 1024
#define H_DIM 8
#define S_DIM 1024
#define C_DIM 128
#define KD 1024  // K depth of both projection GEMMs
#define SCALE 0.08838834764831845f  // 1/sqrt(128)

typedef __attribute__((ext_vector_type(8))) short s16x8;
typedef __attribute__((ext_vector_type(4))) float f32x4;

__device__ __forceinline__ void gll16(const void* g, void* l) {
  __builtin_amdgcn_global_load_lds(
      (const __attribute__((address_space(1))) unsigned int*)g,
      (__attribute__((address_space(3))) unsigned int*)l, 16, 0, 0);
}
__device__ __forceinline__ unsigned short f2bf(float f) {
  unsigned u = __float_as_uint(f);
  u += 0x7FFF + ((u >> 16) & 1u);
  return (unsigned short)(u >> 16);
}
#define MFMA16(a, b, c) __builtin_amdgcn_mfma_f32_16x16x32_bf16(a, b, c, 0, 0, 0)

// ---------------------------------------------------------------------------
// Mask storage detection (bool may arrive as u8 / i32 / f32).
// ---------------------------------------------------------------------------
__global__ void detect_mask(const unsigned char* __restrict__ mask_raw, int* __restrict__ flag) {
  __shared__ int not01, notf;
  if (threadIdx.x == 0) { not01 = 0; notf = 0; }
  __syncthreads();
  const unsigned int* p = (const unsigned int*)mask_raw;
  int l01 = 0, lf = 0;
  for (int i = threadIdx.x; i < 4096; i += 256) {
    unsigned int v = p[i];
    if (v != 0u && v != 1u) l01 = 1;
    if (v != 0u && v != 0x3F800000u) lf = 1;
  }
  if (l01) atomicOr(&not01, 1);
  if (lf) atomicOr(&notf, 1);
  __syncthreads();
  if (threadIdx.x == 0) flag[0] = (!not01) ? 0 : ((!notf) ? 2 : 1);
}

// ---------------------------------------------------------------------------
// Pack mask into k-major bit-words: bits[kt][b][q], word = 64 k bits.
// ---------------------------------------------------------------------------
__global__ __launch_bounds__(256) void pack_mask(const unsigned char* __restrict__ mask_raw,
                                                 const int* __restrict__ flag,
                                                 unsigned long long* __restrict__ bits) {
  __shared__ unsigned char tile[64][80];  // [q][k], pad 80 keeps 16B alignment
  const int t = threadIdx.x;
  const int kt = blockIdx.x * 64, qw = blockIdx.y, b = blockIdx.z;
  const int mk = flag[0];
  const int q = t >> 2, kbase = (t & 3) * 16;
  const size_t row = (size_t)(b * S_DIM + qw * 64 + q);
  if (mk == 1) {
    uint4 v = *(const uint4*)(mask_raw + (row << 10) + kt + kbase);
    *(uint4*)&tile[q][kbase] = v;
  } else if (mk == 0) {
    const int* p = (const int*)mask_raw + (row << 10) + kt + kbase;
#pragma unroll
    for (int j = 0; j < 4; ++j) {
      int4 v = ((const int4*)p)[j];
      uchar4 o;
      o.x = v.x ? 1 : 0; o.y = v.y ? 1 : 0; o.z = v.z ? 1 : 0; o.w = v.w ? 1 : 0;
      *(uchar4*)&tile[q][kbase + j * 4] = o;
    }
  } else {
    const float* p = (const float*)mask_raw + (row << 10) + kt + kbase;
#pragma unroll
    for (int j = 0; j < 4; ++j) {
      float4 v = ((const float4*)p)[j];
      uchar4 o;
      o.x = (v.x != 0.f) ? 1 : 0; o.y = (v.y != 0.f) ? 1 : 0;
      o.z = (v.z != 0.f) ? 1 : 0; o.w = (v.w != 0.f) ? 1 : 0;
      *(uchar4*)&tile[q][kbase + j * 4] = o;
    }
  }
  __syncthreads();
  const int wave = t >> 6, lane = t & 63;
#pragma unroll
  for (int qq = 0; qq < 16; ++qq) {
    int qr = wave * 16 + qq;
    unsigned long long bal = __ballot(tile[qr][lane] != 0);
    if (lane == 0)
      bits[(size_t)blockIdx.x * (B_DIM * S_DIM) + (size_t)b * S_DIM + qw * 64 + qr] = bal;
  }
}

// invm from packed bits: rowsum = sum_kt popcount(bits[kt][b][q])
__global__ __launch_bounds__(256) void invm_from_bits(const unsigned long long* __restrict__ bits,
                                                      float* __restrict__ invm) {
  int idx = blockIdx.x * 256 + threadIdx.x;  // = b*S + q
  int s = 0;
#pragma unroll
  for (int kt = 0; kt < S_DIM / 64; ++kt)
    s += __popcll(bits[(size_t)kt * (B_DIM * S_DIM) + idx]);
  invm[idx] = (s > 0) ? (SCALE / (float)s) : 0.f;
}

// fp32 -> bf16 elementwise (weights)
__global__ __launch_bounds__(256) void cvt_bf16(const float* __restrict__ in,
                                                unsigned short* __restrict__ out, int n) {
  int i = (blockIdx.x * 256 + threadIdx.x) * 4;
  if (i < n) {
    float4 v = *(const float4*)(in + i);
    ushort4 o;
    o.x = f2bf(v.x); o.y = f2bf(v.y); o.z = f2bf(v.z); o.w = f2bf(v.w);
    *(ushort4*)(out + i) = o;
  }
}

// x[b][u][s] f32 -> xT[b][s][u] bf16   (32x32 tiles)
__global__ __launch_bounds__(256) void transpose_x(const float* __restrict__ x,
                                                   unsigned short* __restrict__ xT) {
  __shared__ float T[32][33];
  const int t = threadIdx.x, r = t >> 3, c4 = (t & 7) * 4;
  const int s0 = blockIdx.x * 32, u0 = blockIdx.y * 32;
  const size_t base = (size_t)blockIdx.z * U_DIM * S_DIM;
  float4 v = *(const float4*)(x + base + (size_t)(u0 + r) * S_DIM + s0 + c4);
  T[r][c4 + 0] = v.x; T[r][c4 + 1] = v.y; T[r][c4 + 2] = v.z; T[r][c4 + 3] = v.w;
  __syncthreads();
  ushort4 o;
  o.x = f2bf(T[c4 + 0][r]); o.y = f2bf(T[c4 + 1][r]);
  o.z = f2bf(T[c4 + 2][r]); o.w = f2bf(T[c4 + 3][r]);
  *(ushort4*)(xT + base + (size_t)(s0 + r) * U_DIM + u0 + c4) = o;
}

// qkvT[b][k][2048+c] bf16 -> VT[b][c][k] bf16  (32x32 tiles)
__global__ __launch_bounds__(256) void transpose_v(const unsigned short* __restrict__ qkvT,
                                                   unsigned short* __restrict__ VT) {
  __shared__ unsigned short T[32][34];
  const int t = threadIdx.x, r = t >> 3, c4 = (t & 7) * 4;
  const int k0 = blockIdx.x * 32, c0 = blockIdx.y * 32;
  const unsigned short* qb = qkvT + (size_t)blockIdx.z * S_DIM * (3 * U_DIM);
  ushort4 v = *(const ushort4*)(qb + (size_t)(k0 + r) * (3 * U_DIM) + 2 * U_DIM + c0 + c4);
  T[r][c4 + 0] = v.x; T[r][c4 + 1] = v.y; T[r][c4 + 2] = v.z; T[r][c4 + 3] = v.w;
  __syncthreads();
  ushort4 o;
  o.x = T[c4 + 0][r]; o.y = T[c4 + 1][r]; o.z = T[c4 + 2][r]; o.w = T[c4 + 3][r];
  *(ushort4*)(VT + (size_t)blockIdx.z * U_DIM * S_DIM + (size_t)(c0 + r) * S_DIM + k0 + c4) = o;
}

// ---------------------------------------------------------------------------
// 256x256 tile, BK=64, double-buffered 4-phase K-loop with counted vmcnt
// (R3 version — best measured: 113.6-114.6 us, MfmaUtil ~37%).
// ---------------------------------------------------------------------------
template <typename OUT>
__global__ __launch_bounds__(512, 2) void gemm256(const unsigned short* __restrict__ A,
                                                  const unsigned short* __restrict__ Bm,
                                                  OUT* __restrict__ D,
                                                  long long sAb, long long sBb, long long sDb,
                                                  int N) {
  __shared__ unsigned short sA0[256 * 64], sB0[256 * 64];
  __shared__ unsigned short sA1[256 * 64], sB1[256 * 64];
  const int tid = threadIdx.x;
  const int wave = tid >> 6, lane = tid & 63;
  const int l15 = lane & 15, quad = lane >> 4;
  const int wm = wave & 3, wn = wave >> 2;
  // bijective XCD swizzle (nwg % 8 == 0 at all call sites)
  const unsigned int Lb = blockIdx.x + gridDim.x * (blockIdx.y + gridDim.y * blockIdx.z);
  const unsigned int nwg = gridDim.x * gridDim.y * gridDim.z;
  const unsigned int logical = (Lb & 7u) * (nwg >> 3) + (Lb >> 3);
  const int bx = logical % gridDim.x;
  const unsigned int rem = logical / gridDim.x;
  const int by = rem % gridDim.y;
  const int bz = rem / gridDim.y;
  const int m0 = by * 256, n0 = bx * 256;
  A += (size_t)bz * sAb + (size_t)m0 * KD;
  Bm += (size_t)bz * sBb + (size_t)n0 * KD;
  D += (size_t)bz * sDb;

  // staging coords: thread covers rows r0 / 64+r0 (pass 0/1) of each unit,
  // source chunk kc0 = (tid&7) ^ (r0&7)  (same involution on the read side)
  const int r0 = tid >> 3;                 // 0..63
  const int kc0 = (tid & 7) ^ (r0 & 7);
  const unsigned short* pA = A + (size_t)r0 * KD + kc0 * 8;
  const unsigned short* pB = Bm + (size_t)r0 * KD + kc0 * 8;
  const int wo = wave * 512;               // per-wave LDS dest base (shorts)

#define STG_U0(SA, K0)                                        \
  do {                                                        \
    gll16(pA + (K0), &(SA)[wo]);                              \
    gll16(pA + 64 * KD + (K0), &(SA)[4096 + wo]);             \
  } while (0)
#define STG_U1(SA, K0)                                        \
  do {                                                        \
    gll16(pA + 128 * KD + (K0), &(SA)[8192 + wo]);            \
    gll16(pA + 192 * KD + (K0), &(SA)[12288 + wo]);           \
  } while (0)
#define STG_U2(SB, K0)                                        \
  do {                                                        \
    gll16(pB + (K0), &(SB)[wo]);                              \
    gll16(pB + 128 * KD + (K0), &(SB)[8192 + wo]);            \
  } while (0)
#define STG_U3(SB, K0)                                        \
  do {                                                        \
    gll16(pB + 64 * KD + (K0), &(SB)[4096 + wo]);             \
    gll16(pB + 192 * KD + (K0), &(SB)[12288 + wo]);           \
  } while (0)

#define WAITB(VN)                                             \
  do {                                                        \
    asm volatile("s_waitcnt vmcnt(" #VN ")" ::: "memory");    \
    __builtin_amdgcn_s_barrier();                             \
    asm volatile("" ::: "memory");                            \
  } while (0)

  s16x8 a[4][2];
  f32x4 acc[4][8] = {};

#define LDA(SA)                                                                         \
  do {                                                                                  \
    _Pragma("unroll") for (int i = 0; i < 4; ++i) {                                     \
      int row = wm * 64 + i * 16 + l15;                                                 \
      _Pragma("unroll") for (int ks = 0; ks < 2; ++ks)                                  \
          a[i][ks] = *(const s16x8*)&(SA)[row * 64 + (((ks * 4 + quad) ^ (row & 7)) * 8)]; \
    }                                                                                   \
  } while (0)

#define PHASE(SB, P)                                                                    \
  do {                                                                                  \
    s16x8 b[2][2];                                                                      \
    _Pragma("unroll") for (int jj = 0; jj < 2; ++jj) {                                  \
      int row = wn * 128 + ((P) * 2 + jj) * 16 + l15;                                   \
      _Pragma("unroll") for (int ks = 0; ks < 2; ++ks)                                  \
          b[jj][ks] = *(const s16x8*)&(SB)[row * 64 + (((ks * 4 + quad) ^ (row & 7)) * 8)]; \
    }                                                                                   \
    __builtin_amdgcn_s_setprio(1);                                                      \
    _Pragma("unroll") for (int ks = 0; ks < 2; ++ks)                                    \
        _Pragma("unroll") for (int i = 0; i < 4; ++i)                                   \
            _Pragma("unroll") for (int jj = 0; jj < 2; ++jj)                            \
                acc[i][(P) * 2 + jj] = MFMA16(a[i][ks], b[jj][ks], acc[i][(P) * 2 + jj]); \
    __builtin_amdgcn_s_setprio(0);                                                      \
  } while (0)

  // TILE(t): compute from (SA,SB), stage tile t+1 units into (SAn,SBn) at K1.
#define TILE(SA, SB, SAn, SBn, K1)                            \
  do {                                                        \
    WAITB(2);                                                 \
    STG_U0(SAn, K1);                                          \
    LDA(SA);                                                  \
    PHASE(SB, 0);                                             \
    STG_U1(SAn, K1);                                          \
    PHASE(SB, 1);                                             \
    WAITB(4);                                                 \
    STG_U2(SBn, K1);                                          \
    PHASE(SB, 2);                                             \
    STG_U3(SBn, K1);                                          \
    PHASE(SB, 3);                                             \
  } while (0)

  // final tile: no staging; full drain before P3's U3 reads
#define TILE_LAST(CA, CB)                                     \
  do {                                                        \
    WAITB(2);                                                 \
    LDA(CA);                                                  \
    PHASE(CB, 0);                                             \
    PHASE(CB, 1);                                             \
    WAITB(0);                                                 \
    PHASE(CB, 2);                                             \
    PHASE(CB, 3);                                             \
  } while (0)

  // prologue: tile 0's 4 units (8 loads in flight)
  STG_U0(sA0, 0); STG_U1(sA0, 0); STG_U2(sB0, 0); STG_U3(sB0, 0);

  for (int kt = 0; kt < 14; kt += 2) {
    TILE(sA0, sB0, sA1, sB1, (kt + 1) * 64);
    TILE(sA1, sB1, sA0, sB0, (kt + 2) * 64);
  }
  TILE(sA0, sB0, sA1, sB1, 15 * 64);  // tile 14, stages tile 15
  TILE_LAST(sA1, sB1);                // tile 15
#undef TILE
#undef TILE_LAST
#undef PHASE
#undef LDA
#undef WAITB
#undef STG_U0
#undef STG_U1
#undef STG_U2
#undef STG_U3

#pragma unroll
  for (int i = 0; i < 4; ++i)
#pragma unroll
    for (int j = 0; j < 8; ++j) {
      f32x4 v = acc[i][j];
#pragma unroll
      for (int r = 0; r < 4; ++r) {
        int m = m0 + wm * 64 + i * 16 + quad * 4 + r;
        int n = n0 + wn * 128 + j * 16 + l15;
        if constexpr (sizeof(OUT) == 2) D[(size_t)m * N + n] = f2bf(v[r]);
        else D[(size_t)m * N + n] = v[r];
      }
    }
}

// ---------------------------------------------------------------------------
// Fused masked-relu attention, QBLK=128, 512 threads / 8 waves, LDS = 64 KB
// (2 blocks/CU -> 4 waves/SIMD). Q is staged in TWO 16 KB halves through QV:
// half0 -> qhalf=0 waves read fragments -> barrier -> half1 -> qhalf=1 read.
// After the prologue QV is exactly V-ping-sized ([128][64]).
// wave = (qhalf = wave>>2, kw = wave&3); V(t+1) prestaged at iter start into
// the dead V buffer; K(t+1) staged after the P-ready barrier.
// ---------------------------------------------------------------------------
__global__ __launch_bounds__(512, 2) void attn_mfma(const unsigned short* __restrict__ qkvT,
                                                    const unsigned short* __restrict__ VT,
                                                    const unsigned long long* __restrict__ bits,
                                                    const float* __restrict__ invm,
                                                    unsigned short* __restrict__ CcT, int b0) {
  __shared__ unsigned short QV[64 * 128];   // Q half staging, then V ping (16 KB)
  __shared__ unsigned short Ks[64 * 128];   // [k][c] swizzled (16 KB)
  __shared__ unsigned short Vs[128 * 64];   // [c][k] swizzled (16 KB)
  __shared__ unsigned short Ps[128 * 64];   // [q][k] swizzled (16 KB)

  const int tid = threadIdx.x, wave = tid >> 6, lane = tid & 63;
  const int l15 = lane & 15, quad = lane >> 4;
  const int qhalf = wave >> 2, kw = wave & 3;
  // bijective XCD swizzle: nwg = 64*gridDim.z, always % 8 == 0.
  const int L = blockIdx.x + 8 * (blockIdx.y + 8 * blockIdx.z);
  const int cpx = (8 * H_DIM * gridDim.z) >> 3;
  const int logical = (L & 7) * cpx + (L >> 3);
  const int qt = logical & 7, h = (logical >> 3) & 7, z = logical >> 6;
  const int q0 = qt * 128, b = b0 + z;
  const unsigned short* qB = qkvT + (size_t)z * S_DIM * (3 * U_DIM);
  const unsigned short* Vb = VT + (size_t)z * U_DIM * S_DIM + (size_t)h * C_DIM * S_DIM;

  // prologue pass 1: Q half0 -> QV, K(0) -> Ks, V(0) -> Vs
#pragma unroll
  for (int pp = 0; pp < 2; ++pp) {
    int p = pp * 512 + tid;
    int row = p >> 4, c = (p & 15) ^ (row & 7);
    gll16(qB + (size_t)(q0 + row) * (3 * U_DIM) + h * C_DIM + c * 8, &QV[p * 8]);
    gll16(qB + (size_t)row * (3 * U_DIM) + U_DIM + h * C_DIM + c * 8, &Ks[p * 8]);
    int vrow = p >> 3, vkc = (p & 7) ^ (vrow & 7);
    gll16(Vb + (size_t)vrow * S_DIM + vkc * 8, &Vs[p * 8]);
  }
  __syncthreads();

  // qhalf=0 waves read their Q fragments (local rows 0..63 = global q0+row)
  s16x8 qf[4][4];
  if (qhalf == 0) {
#pragma unroll
    for (int j = 0; j < 4; ++j)
#pragma unroll
      for (int kk = 0; kk < 4; ++kk) {
        int row = j * 16 + l15;
        qf[j][kk] = *(const s16x8*)&QV[row * 128 + ((kk * 4 + quad) ^ (row & 7)) * 8];
      }
  }
  __syncthreads();  // half0 fragment reads complete before overwrite

  // prologue pass 2: Q half1 -> QV
#pragma unroll
  for (int pp = 0; pp < 2; ++pp) {
    int p = pp * 512 + tid;
    int row = p >> 4, c = (p & 15) ^ (row & 7);
    gll16(qB + (size_t)(q0 + 64 + row) * (3 * U_DIM) + h * C_DIM + c * 8, &QV[p * 8]);
  }
  __syncthreads();

  if (qhalf == 1) {
#pragma unroll
    for (int j = 0; j < 4; ++j)
#pragma unroll
      for (int kk = 0; kk < 4; ++kk) {
        int row = j * 16 + l15;
        qf[j][kk] = *(const s16x8*)&QV[row * 128 + ((kk * 4 + quad) ^ (row & 7)) * 8];
      }
  }
  float invf[4];
  {
    const float* ivp = invm + (size_t)b * S_DIM + q0 + qhalf * 64;
#pragma unroll
    for (int j = 0; j < 4; ++j) invf[j] = ivp[j * 16 + l15];
  }
  __syncthreads();  // half1 fragment reads done before V(1) prestage hits QV

  f32x4 pacc[4][2] = {};

  for (int kt = 0; kt < S_DIM / 64; ++kt) {
    // prestage V(t+1) into the buffer NOT read this iter (dead since the
    // end barrier of iter kt-1) — full iteration to cover HBM latency
    if (kt < S_DIM / 64 - 1) {
      const int kn = (kt + 1) * 64;
      unsigned short* vdst = (kt & 1) ? Vs : QV;
#pragma unroll
      for (int pp = 0; pp < 2; ++pp) {
        int p = pp * 512 + tid;
        int vrow = p >> 3, vkc = (p & 7) ^ (vrow & 7);
        gll16(Vb + (size_t)vrow * S_DIM + kn + vkc * 8, &vdst[p * 8]);
      }
    }

    // mask words: 64 k-bits at q = q0 + qhalf*64 + j*16 + l15
    unsigned long long w64[4];
    {
      const unsigned long long* mw =
          bits + (size_t)kt * (B_DIM * S_DIM) + (size_t)b * S_DIM + q0 + qhalf * 64;
#pragma unroll
      for (int j = 0; j < 4; ++j) w64[j] = mw[j * 16 + l15];
    }

    // scores D[k][q]: wave handles k rows [kw*16, kw*16+16), q = own half
    s16x8 af[4];
#pragma unroll
    for (int kk = 0; kk < 4; ++kk) {
      int row = kw * 16 + l15;
      af[kk] = *(const s16x8*)&Ks[row * 128 + ((kk * 4 + quad) ^ (row & 7)) * 8];
    }
    f32x4 sacc[4] = {};
    __builtin_amdgcn_s_setprio(1);
#pragma unroll
    for (int kk = 0; kk < 4; ++kk)
#pragma unroll
      for (int j = 0; j < 4; ++j) sacc[j] = MFMA16(af[kk], qf[j][kk], sacc[j]);
    __builtin_amdgcn_s_setprio(0);

    // P = maskbit * relu(s) * scale/m -> packed bf16 -> LDS
#pragma unroll
    for (int j = 0; j < 4; ++j) {
      const unsigned int m4 = (unsigned int)(w64[j] >> (kw * 16 + quad * 4)) & 0xFu;
      float p[4];
#pragma unroll
      for (int r = 0; r < 4; ++r) {
        float t = fmaxf(sacc[j][r], 0.f) * invf[j];
        p[r] = ((m4 >> r) & 1u) ? t : 0.f;
      }
      unsigned int pk0, pk1;
      asm("v_cvt_pk_bf16_f32 %0, %1, %2" : "=v"(pk0) : "v"(p[0]), "v"(p[1]));
      asm("v_cvt_pk_bf16_f32 %0, %1, %2" : "=v"(pk1) : "v"(p[2]), "v"(p[3]));
      int q = qhalf * 64 + j * 16 + l15;
      int chunk = (kw * 2 + (quad >> 1)) ^ (q & 7);
      *(uint2*)&Ps[q * 64 + chunk * 8 + (quad & 1) * 4] = make_uint2(pk0, pk1);
    }
    __syncthreads();  // P ready; all waves done reading Ks

    // stage K(t+1) -> Ks while PV computes
    if (kt < S_DIM / 64 - 1) {
      const int kn = (kt + 1) * 64;
#pragma unroll
      for (int pp = 0; pp < 2; ++pp) {
        int p = pp * 512 + tid;
        int row = p >> 4, c = (p & 15) ^ (row & 7);
        gll16(qB + (size_t)(kn + row) * (3 * U_DIM) + U_DIM + h * C_DIM + c * 8, &Ks[p * 8]);
      }
    }

    // PV from V(kt) (even -> Vs, odd -> QV): q-half rows x c-cols [kw*32,+32)
    const unsigned short* vbuf = (kt & 1) ? QV : Vs;
#pragma unroll
    for (int ks = 0; ks < 2; ++ks) {
      s16x8 pf[4], vf[2];
#pragma unroll
      for (int i = 0; i < 4; ++i) {
        int row = qhalf * 64 + i * 16 + l15;
        pf[i] = *(const s16x8*)&Ps[row * 64 + ((ks * 4 + quad) ^ (row & 7)) * 8];
      }
#pragma unroll
      for (int j = 0; j < 2; ++j) {
        int row = kw * 32 + j * 16 + l15;
        vf[j] = *(const s16x8*)&vbuf[row * 64 + ((ks * 4 + quad) ^ (row & 7)) * 8];
      }
      __builtin_amdgcn_s_setprio(1);
#pragma unroll
      for (int i = 0; i < 4; ++i)
#pragma unroll
        for (int j = 0; j < 2; ++j) pacc[i][j] = MFMA16(pf[i], vf[j], pacc[i][j]);
      __builtin_amdgcn_s_setprio(0);
    }
    __syncthreads();  // PV done + staging drained (vmcnt(0) at barrier)
  }

  // epilogue: CcT[b][q][h*128+c] bf16
  unsigned short* cb = CcT + (size_t)z * S_DIM * U_DIM;
#pragma unroll
  for (int i = 0; i < 4; ++i)
#pragma unroll
    for (int j = 0; j < 2; ++j) {
      f32x4 v = pacc[i][j];
#pragma unroll
      for (int r = 0; r < 4; ++r) {
        int q = q0 + qhalf * 64 + i * 16 + quad * 4 + r;
        int c = h * C_DIM + kw * 32 + j * 16 + l15;
        cb[(size_t)q * U_DIM + c] = f2bf(v[r]);
      }
    }
}

// ---------------------------------------------------------------------------
extern "C" void kernel_launch(void* const* d_in, const int* in_sizes, int n_in,
                              void* d_out, int out_size, void* d_ws, size_t ws_size,
                              hipStream_t stream) {
  const float* x = (const float*)d_in[0];
  const unsigned char* mask_raw = (const unsigned char*)d_in[1];
  const float* w_qkv = (const float*)d_in[2];
  const float* w_out = (const float*)d_in[3];
  float* out = (float*)d_out;

  char* ws = (char*)d_ws;
  int* flag = (int*)ws;                                  // 256 B
  float* invm = (float*)(ws + 256);                      // 64 KB
  unsigned long long* bits = (unsigned long long*)(ws + 256 + 65536);  // 2 MB
  unsigned short* wqkv_bf = (unsigned short*)((char*)bits + (size_t)B_DIM * S_DIM * 16 * 8);
  unsigned short* wout_bf = (unsigned short*)((char*)wqkv_bf + (size_t)3 * U_DIM * U_DIM * 2);
  char* heap = (char*)wout_bf + (size_t)U_DIM * U_DIM * 2;

  const size_t xT_pb = (size_t)U_DIM * S_DIM * 2;
  const size_t qkvT_pb = (size_t)3 * U_DIM * S_DIM * 2;
  const size_t vT_pb = (size_t)U_DIM * S_DIM * 2;
  const size_t ccT_pb = (size_t)U_DIM * S_DIM * 2;
  const size_t per_batch = xT_pb + qkvT_pb + vT_pb + ccT_pb;  // 12.58 MB
  const size_t fixed = (size_t)(heap - ws);
  int nb = (ws_size > fixed) ? (int)((ws_size - fixed) / per_batch) : 1;
  if (nb < 1) nb = 1;
  if (nb > B_DIM) nb = B_DIM;

  unsigned short* xT = (unsigned short*)heap;
  unsigned short* qkvT = (unsigned short*)(heap + (size_t)nb * xT_pb);
  unsigned short* VT = (unsigned short*)(heap + (size_t)nb * (xT_pb + qkvT_pb));
  unsigned short* CcT = (unsigned short*)(heap + (size_t)nb * (xT_pb + qkvT_pb + vT_pb));

  detect_mask<<<1, 256, 0, stream>>>(mask_raw, flag);
  pack_mask<<<dim3(S_DIM / 64, S_DIM / 64, B_DIM), 256, 0, stream>>>(mask_raw, flag, bits);
  invm_from_bits<<<(B_DIM * S_DIM) / 256, 256, 0, stream>>>(bits, invm);
  cvt_bf16<<<(3 * U_DIM * U_DIM) / 1024, 256, 0, stream>>>(w_qkv, wqkv_bf, 3 * U_DIM * U_DIM);
  cvt_bf16<<<(U_DIM * U_DIM) / 1024, 256, 0, stream>>>(w_out, wout_bf, U_DIM * U_DIM);

  for (int b0 = 0; b0 < B_DIM; b0 += nb) {
    int cnt = (B_DIM - b0 < nb) ? (B_DIM - b0) : nb;
    transpose_x<<<dim3(S_DIM / 32, U_DIM / 32, cnt), 256, 0, stream>>>(
        x + (size_t)b0 * U_DIM * S_DIM, xT);
    gemm256<unsigned short><<<dim3(3 * U_DIM / 256, S_DIM / 256, cnt), 512, 0, stream>>>(
        xT, wqkv_bf, qkvT, (long long)U_DIM * S_DIM, 0LL, (long long)3 * U_DIM * S_DIM, 3 * U_DIM);
    transpose_v<<<dim3(S_DIM / 32, U_DIM / 32, cnt), 256, 0, stream>>>(qkvT, VT);
    attn_mfma<<<dim3(S_DIM / 128, H_DIM, cnt), 512, 0, stream>>>(
        qkvT, VT, bits, invm, CcT, b0);
    gemm256<float><<<dim3(S_DIM / 256, U_DIM / 256, cnt), 512, 0, stream>>>(
        wout_bf, CcT, out + (size_t)b0 * U_DIM * S_DIM, 0LL,
        (long long)U_DIM * S_DIM, (long long)U_DIM * S_DIM, S_DIM);
  }
}

// Round 7
// 444.951 us; speedup vs baseline: 1.0454x; 1.0454x over previous
//
#include <hip/hip_runtime.h>

#define B_DIM 16
#define U_DIM 1024
#define H_DIM 8
#define S_DIM 1024
#define C_DIM 128
#define KD 1024  // K depth of both projection GEMMs
#define SCALE 0.08838834764831845f  // 1/sqrt(128)

typedef __attribute__((ext_vector_type(8))) short s16x8;
typedef __attribute__((ext_vector_type(4))) float f32x4;

__device__ __forceinline__ void gll16(const void* g, void* l) {
  __builtin_amdgcn_global_load_lds(
      (const __attribute__((address_space(1))) unsigned int*)g,
      (__attribute__((address_space(3))) unsigned int*)l, 16, 0, 0);
}
__device__ __forceinline__ unsigned short f2bf(float f) {
  unsigned u = __float_as_uint(f);
  u += 0x7FFF + ((u >> 16) & 1u);
  return (unsigned short)(u >> 16);
}
#define MFMA16(a, b, c) __builtin_amdgcn_mfma_f32_16x16x32_bf16(a, b, c, 0, 0, 0)

// ---------------------------------------------------------------------------
// Mask storage detection (bool may arrive as u8 / i32 / f32).
// ---------------------------------------------------------------------------
__global__ void detect_mask(const unsigned char* __restrict__ mask_raw, int* __restrict__ flag) {
  __shared__ int not01, notf;
  if (threadIdx.x == 0) { not01 = 0; notf = 0; }
  __syncthreads();
  const unsigned int* p = (const unsigned int*)mask_raw;
  int l01 = 0, lf = 0;
  for (int i = threadIdx.x; i < 4096; i += 256) {
    unsigned int v = p[i];
    if (v != 0u && v != 1u) l01 = 1;
    if (v != 0u && v != 0x3F800000u) lf = 1;
  }
  if (l01) atomicOr(&not01, 1);
  if (lf) atomicOr(&notf, 1);
  __syncthreads();
  if (threadIdx.x == 0) flag[0] = (!not01) ? 0 : ((!notf) ? 2 : 1);
}

// ---------------------------------------------------------------------------
// Pack mask into k-major bit-words: bits[kt][b][q], word = 64 k bits.
// ---------------------------------------------------------------------------
__global__ __launch_bounds__(256) void pack_mask(const unsigned char* __restrict__ mask_raw,
                                                 const int* __restrict__ flag,
                                                 unsigned long long* __restrict__ bits) {
  __shared__ unsigned char tile[64][80];  // [q][k], pad 80 keeps 16B alignment
  const int t = threadIdx.x;
  const int kt = blockIdx.x * 64, qw = blockIdx.y, b = blockIdx.z;
  const int mk = flag[0];
  const int q = t >> 2, kbase = (t & 3) * 16;
  const size_t row = (size_t)(b * S_DIM + qw * 64 + q);
  if (mk == 1) {
    uint4 v = *(const uint4*)(mask_raw + (row << 10) + kt + kbase);
    *(uint4*)&tile[q][kbase] = v;
  } else if (mk == 0) {
    const int* p = (const int*)mask_raw + (row << 10) + kt + kbase;
#pragma unroll
    for (int j = 0; j < 4; ++j) {
      int4 v = ((const int4*)p)[j];
      uchar4 o;
      o.x = v.x ? 1 : 0; o.y = v.y ? 1 : 0; o.z = v.z ? 1 : 0; o.w = v.w ? 1 : 0;
      *(uchar4*)&tile[q][kbase + j * 4] = o;
    }
  } else {
    const float* p = (const float*)mask_raw + (row << 10) + kt + kbase;
#pragma unroll
    for (int j = 0; j < 4; ++j) {
      float4 v = ((const float4*)p)[j];
      uchar4 o;
      o.x = (v.x != 0.f) ? 1 : 0; o.y = (v.y != 0.f) ? 1 : 0;
      o.z = (v.z != 0.f) ? 1 : 0; o.w = (v.w != 0.f) ? 1 : 0;
      *(uchar4*)&tile[q][kbase + j * 4] = o;
    }
  }
  __syncthreads();
  const int wave = t >> 6, lane = t & 63;
#pragma unroll
  for (int qq = 0; qq < 16; ++qq) {
    int qr = wave * 16 + qq;
    unsigned long long bal = __ballot(tile[qr][lane] != 0);
    if (lane == 0)
      bits[(size_t)blockIdx.x * (B_DIM * S_DIM) + (size_t)b * S_DIM + qw * 64 + qr] = bal;
  }
}

// invm from packed bits: rowsum = sum_kt popcount(bits[kt][b][q])
__global__ __launch_bounds__(256) void invm_from_bits(const unsigned long long* __restrict__ bits,
                                                      float* __restrict__ invm) {
  int idx = blockIdx.x * 256 + threadIdx.x;  // = b*S + q
  int s = 0;
#pragma unroll
  for (int kt = 0; kt < S_DIM / 64; ++kt)
    s += __popcll(bits[(size_t)kt * (B_DIM * S_DIM) + idx]);
  invm[idx] = (s > 0) ? (SCALE / (float)s) : 0.f;
}

// fp32 -> bf16 elementwise (weights)
__global__ __launch_bounds__(256) void cvt_bf16(const float* __restrict__ in,
                                                unsigned short* __restrict__ out, int n) {
  int i = (blockIdx.x * 256 + threadIdx.x) * 4;
  if (i < n) {
    float4 v = *(const float4*)(in + i);
    ushort4 o;
    o.x = f2bf(v.x); o.y = f2bf(v.y); o.z = f2bf(v.z); o.w = f2bf(v.w);
    *(ushort4*)(out + i) = o;
  }
}

// x[b][u][s] f32 -> xT[b][s][u] bf16   (32x32 tiles)
__global__ __launch_bounds__(256) void transpose_x(const float* __restrict__ x,
                                                   unsigned short* __restrict__ xT) {
  __shared__ float T[32][33];
  const int t = threadIdx.x, r = t >> 3, c4 = (t & 7) * 4;
  const int s0 = blockIdx.x * 32, u0 = blockIdx.y * 32;
  const size_t base = (size_t)blockIdx.z * U_DIM * S_DIM;
  float4 v = *(const float4*)(x + base + (size_t)(u0 + r) * S_DIM + s0 + c4);
  T[r][c4 + 0] = v.x; T[r][c4 + 1] = v.y; T[r][c4 + 2] = v.z; T[r][c4 + 3] = v.w;
  __syncthreads();
  ushort4 o;
  o.x = f2bf(T[c4 + 0][r]); o.y = f2bf(T[c4 + 1][r]);
  o.z = f2bf(T[c4 + 2][r]); o.w = f2bf(T[c4 + 3][r]);
  *(ushort4*)(xT + base + (size_t)(s0 + r) * U_DIM + u0 + c4) = o;
}

// qkvT[b][k][2048+c] bf16 -> VT[b][c][k] bf16  (32x32 tiles)
__global__ __launch_bounds__(256) void transpose_v(const unsigned short* __restrict__ qkvT,
                                                   unsigned short* __restrict__ VT) {
  __shared__ unsigned short T[32][34];
  const int t = threadIdx.x, r = t >> 3, c4 = (t & 7) * 4;
  const int k0 = blockIdx.x * 32, c0 = blockIdx.y * 32;
  const unsigned short* qb = qkvT + (size_t)blockIdx.z * S_DIM * (3 * U_DIM);
  ushort4 v = *(const ushort4*)(qb + (size_t)(k0 + r) * (3 * U_DIM) + 2 * U_DIM + c0 + c4);
  T[r][c4 + 0] = v.x; T[r][c4 + 1] = v.y; T[r][c4 + 2] = v.z; T[r][c4 + 3] = v.w;
  __syncthreads();
  ushort4 o;
  o.x = T[c4 + 0][r]; o.y = T[c4 + 1][r]; o.z = T[c4 + 2][r]; o.w = T[c4 + 3][r];
  *(ushort4*)(VT + (size_t)blockIdx.z * U_DIM * S_DIM + (size_t)(c0 + r) * S_DIM + k0 + c4) = o;
}

// ---------------------------------------------------------------------------
// 256x256 tile, BK=64, double-buffered 4-phase K-loop with counted vmcnt
// (R3 version — best measured: 113.6-114.6 us, MfmaUtil ~37%).
// ---------------------------------------------------------------------------
template <typename OUT>
__global__ __launch_bounds__(512, 2) void gemm256(const unsigned short* __restrict__ A,
                                                  const unsigned short* __restrict__ Bm,
                                                  OUT* __restrict__ D,
                                                  long long sAb, long long sBb, long long sDb,
                                                  int N) {
  __shared__ unsigned short sA0[256 * 64], sB0[256 * 64];
  __shared__ unsigned short sA1[256 * 64], sB1[256 * 64];
  const int tid = threadIdx.x;
  const int wave = tid >> 6, lane = tid & 63;
  const int l15 = lane & 15, quad = lane >> 4;
  const int wm = wave & 3, wn = wave >> 2;
  // bijective XCD swizzle (nwg % 8 == 0 at all call sites)
  const unsigned int Lb = blockIdx.x + gridDim.x * (blockIdx.y + gridDim.y * blockIdx.z);
  const unsigned int nwg = gridDim.x * gridDim.y * gridDim.z;
  const unsigned int logical = (Lb & 7u) * (nwg >> 3) + (Lb >> 3);
  const int bx = logical % gridDim.x;
  const unsigned int rem = logical / gridDim.x;
  const int by = rem % gridDim.y;
  const int bz = rem / gridDim.y;
  const int m0 = by * 256, n0 = bx * 256;
  A += (size_t)bz * sAb + (size_t)m0 * KD;
  Bm += (size_t)bz * sBb + (size_t)n0 * KD;
  D += (size_t)bz * sDb;

  // staging coords: thread covers rows r0 / 64+r0 (pass 0/1) of each unit,
  // source chunk kc0 = (tid&7) ^ (r0&7)  (same involution on the read side)
  const int r0 = tid >> 3;                 // 0..63
  const int kc0 = (tid & 7) ^ (r0 & 7);
  const unsigned short* pA = A + (size_t)r0 * KD + kc0 * 8;
  const unsigned short* pB = Bm + (size_t)r0 * KD + kc0 * 8;
  const int wo = wave * 512;               // per-wave LDS dest base (shorts)

#define STG_U0(SA, K0)                                        \
  do {                                                        \
    gll16(pA + (K0), &(SA)[wo]);                              \
    gll16(pA + 64 * KD + (K0), &(SA)[4096 + wo]);             \
  } while (0)
#define STG_U1(SA, K0)                                        \
  do {                                                        \
    gll16(pA + 128 * KD + (K0), &(SA)[8192 + wo]);            \
    gll16(pA + 192 * KD + (K0), &(SA)[12288 + wo]);           \
  } while (0)
#define STG_U2(SB, K0)                                        \
  do {                                                        \
    gll16(pB + (K0), &(SB)[wo]);                              \
    gll16(pB + 128 * KD + (K0), &(SB)[8192 + wo]);            \
  } while (0)
#define STG_U3(SB, K0)                                        \
  do {                                                        \
    gll16(pB + 64 * KD + (K0), &(SB)[4096 + wo]);             \
    gll16(pB + 192 * KD + (K0), &(SB)[12288 + wo]);           \
  } while (0)

#define WAITB(VN)                                             \
  do {                                                        \
    asm volatile("s_waitcnt vmcnt(" #VN ")" ::: "memory");    \
    __builtin_amdgcn_s_barrier();                             \
    asm volatile("" ::: "memory");                            \
  } while (0)

  s16x8 a[4][2];
  f32x4 acc[4][8] = {};

#define LDA(SA)                                                                         \
  do {                                                                                  \
    _Pragma("unroll") for (int i = 0; i < 4; ++i) {                                     \
      int row = wm * 64 + i * 16 + l15;                                                 \
      _Pragma("unroll") for (int ks = 0; ks < 2; ++ks)                                  \
          a[i][ks] = *(const s16x8*)&(SA)[row * 64 + (((ks * 4 + quad) ^ (row & 7)) * 8)]; \
    }                                                                                   \
  } while (0)

#define PHASE(SB, P)                                                                    \
  do {                                                                                  \
    s16x8 b[2][2];                                                                      \
    _Pragma("unroll") for (int jj = 0; jj < 2; ++jj) {                                  \
      int row = wn * 128 + ((P) * 2 + jj) * 16 + l15;                                   \
      _Pragma("unroll") for (int ks = 0; ks < 2; ++ks)                                  \
          b[jj][ks] = *(const s16x8*)&(SB)[row * 64 + (((ks * 4 + quad) ^ (row & 7)) * 8)]; \
    }                                                                                   \
    __builtin_amdgcn_s_setprio(1);                                                      \
    _Pragma("unroll") for (int ks = 0; ks < 2; ++ks)                                    \
        _Pragma("unroll") for (int i = 0; i < 4; ++i)                                   \
            _Pragma("unroll") for (int jj = 0; jj < 2; ++jj)                            \
                acc[i][(P) * 2 + jj] = MFMA16(a[i][ks], b[jj][ks], acc[i][(P) * 2 + jj]); \
    __builtin_amdgcn_s_setprio(0);                                                      \
  } while (0)

  // TILE(t): compute from (SA,SB), stage tile t+1 units into (SAn,SBn) at K1.
#define TILE(SA, SB, SAn, SBn, K1)                            \
  do {                                                        \
    WAITB(2);                                                 \
    STG_U0(SAn, K1);                                          \
    LDA(SA);                                                  \
    PHASE(SB, 0);                                             \
    STG_U1(SAn, K1);                                          \
    PHASE(SB, 1);                                             \
    WAITB(4);                                                 \
    STG_U2(SBn, K1);                                          \
    PHASE(SB, 2);                                             \
    STG_U3(SBn, K1);                                          \
    PHASE(SB, 3);                                             \
  } while (0)

  // final tile: no staging; full drain before P3's U3 reads
#define TILE_LAST(CA, CB)                                     \
  do {                                                        \
    WAITB(2);                                                 \
    LDA(CA);                                                  \
    PHASE(CB, 0);                                             \
    PHASE(CB, 1);                                             \
    WAITB(0);                                                 \
    PHASE(CB, 2);                                             \
    PHASE(CB, 3);                                             \
  } while (0)

  // prologue: tile 0's 4 units (8 loads in flight)
  STG_U0(sA0, 0); STG_U1(sA0, 0); STG_U2(sB0, 0); STG_U3(sB0, 0);

  for (int kt = 0; kt < 14; kt += 2) {
    TILE(sA0, sB0, sA1, sB1, (kt + 1) * 64);
    TILE(sA1, sB1, sA0, sB0, (kt + 2) * 64);
  }
  TILE(sA0, sB0, sA1, sB1, 15 * 64);  // tile 14, stages tile 15
  TILE_LAST(sA1, sB1);                // tile 15
#undef TILE
#undef TILE_LAST
#undef PHASE
#undef LDA
#undef WAITB
#undef STG_U0
#undef STG_U1
#undef STG_U2
#undef STG_U3

#pragma unroll
  for (int i = 0; i < 4; ++i)
#pragma unroll
    for (int j = 0; j < 8; ++j) {
      f32x4 v = acc[i][j];
#pragma unroll
      for (int r = 0; r < 4; ++r) {
        int m = m0 + wm * 64 + i * 16 + quad * 4 + r;
        int n = n0 + wn * 128 + j * 16 + l15;
        if constexpr (sizeof(OUT) == 2) D[(size_t)m * N + n] = f2bf(v[r]);
        else D[(size_t)m * N + n] = v[r];
      }
    }
}

// ---------------------------------------------------------------------------
// Fused masked-relu attention, QBLK=128, 1024 threads / 16 waves (4/SIMD
// guaranteed within one block — co-residency of a 2nd block never happened).
// wave = (qq = wave>>2 owning 32 q-rows, kw = wave&3 for k/c split).
// LDS 80 KB: QV (V ping; Q half-stage in prologue), Ks0/Ks1 (K double buf),
// Vs, Ps. K(t+1)+V(t+1) prestaged at ITER START into the ^1 buffers; the
// mid-iter P-barrier drains ONLY lgkmcnt (raw s_barrier) so the prestage
// loads ride across it and get the whole iteration to land; the end-of-iter
// __syncthreads (vmcnt 0) is then a free drain.
// Safety: writes to any buffer are separated from its last readers by the
// previous end-of-iter __syncthreads (audited per-buffer).
// ---------------------------------------------------------------------------
__global__ __launch_bounds__(1024, 4) void attn_mfma(const unsigned short* __restrict__ qkvT,
                                                     const unsigned short* __restrict__ VT,
                                                     const unsigned long long* __restrict__ bits,
                                                     const float* __restrict__ invm,
                                                     unsigned short* __restrict__ CcT, int b0) {
  __shared__ unsigned short QV[64 * 128];   // Q half staging, then V ping (16 KB)
  __shared__ unsigned short Ks0[64 * 128];  // K even buf (16 KB)
  __shared__ unsigned short Ks1[64 * 128];  // K odd buf (16 KB)
  __shared__ unsigned short Vs[128 * 64];   // V pong (16 KB)
  __shared__ unsigned short Ps[128 * 64];   // [q][k] swizzled (16 KB)

  const int tid = threadIdx.x, wave = tid >> 6, lane = tid & 63;
  const int l15 = lane & 15, quad = lane >> 4;
  const int qq = wave >> 2, kw = wave & 3;
  // bijective XCD swizzle: nwg = 64*gridDim.z, always % 8 == 0.
  const int L = blockIdx.x + 8 * (blockIdx.y + 8 * blockIdx.z);
  const int cpx = (8 * H_DIM * gridDim.z) >> 3;
  const int logical = (L & 7) * cpx + (L >> 3);
  const int qt = logical & 7, h = (logical >> 3) & 7, z = logical >> 6;
  const int q0 = qt * 128, b = b0 + z;
  const unsigned short* qB = qkvT + (size_t)z * S_DIM * (3 * U_DIM);
  const unsigned short* Vb = VT + (size_t)z * U_DIM * S_DIM + (size_t)h * C_DIM * S_DIM;

  // per-thread staging coords (one 16B chunk per 16KB unit)
  const int srow = tid >> 4, sc = (tid & 15) ^ (srow & 7);     // K/Q layout
  const int vrow = tid >> 3, vkc = (tid & 7) ^ (vrow & 7);     // V layout

  // prologue pass 1: Q half0 -> QV, K(0) -> Ks0, V(0) -> Vs
  gll16(qB + (size_t)(q0 + srow) * (3 * U_DIM) + h * C_DIM + sc * 8, &QV[tid * 8]);
  gll16(qB + (size_t)srow * (3 * U_DIM) + U_DIM + h * C_DIM + sc * 8, &Ks0[tid * 8]);
  gll16(Vb + (size_t)vrow * S_DIM + vkc * 8, &Vs[tid * 8]);
  __syncthreads();

  // waves qq<2 read their Q fragments from half0 (local rows qq*32 + ...)
  s16x8 qf[2][4];
  if (qq < 2) {
#pragma unroll
    for (int j = 0; j < 2; ++j)
#pragma unroll
      for (int kk = 0; kk < 4; ++kk) {
        int row = qq * 32 + j * 16 + l15;
        qf[j][kk] = *(const s16x8*)&QV[row * 128 + ((kk * 4 + quad) ^ (row & 7)) * 8];
      }
  }
  __syncthreads();  // half0 fragment reads complete before overwrite

  // prologue pass 2: Q half1 -> QV
  gll16(qB + (size_t)(q0 + 64 + srow) * (3 * U_DIM) + h * C_DIM + sc * 8, &QV[tid * 8]);
  __syncthreads();

  if (qq >= 2) {
#pragma unroll
    for (int j = 0; j < 2; ++j)
#pragma unroll
      for (int kk = 0; kk < 4; ++kk) {
        int row = (qq - 2) * 32 + j * 16 + l15;
        qf[j][kk] = *(const s16x8*)&QV[row * 128 + ((kk * 4 + quad) ^ (row & 7)) * 8];
      }
  }
  float invf[2];
  {
    const float* ivp = invm + (size_t)b * S_DIM + q0 + qq * 32;
#pragma unroll
    for (int j = 0; j < 2; ++j) invf[j] = ivp[j * 16 + l15];
  }
  __syncthreads();  // half1 fragment reads done before V(1) prestage hits QV

  f32x4 pacc[2][2] = {};

  for (int kt = 0; kt < S_DIM / 64; ++kt) {
    const unsigned short* kcur = (kt & 1) ? Ks1 : Ks0;
    unsigned short* knxt = (kt & 1) ? Ks0 : Ks1;
    const unsigned short* vcur = (kt & 1) ? QV : Vs;
    unsigned short* vnxt = (kt & 1) ? Vs : QV;

    // prestage K(t+1) and V(t+1) at iter start into the ^1 buffers (their
    // last readers finished before the previous end-of-iter barrier)
    if (kt < S_DIM / 64 - 1) {
      const int kn = (kt + 1) * 64;
      gll16(qB + (size_t)(kn + srow) * (3 * U_DIM) + U_DIM + h * C_DIM + sc * 8,
            &knxt[tid * 8]);
      gll16(Vb + (size_t)vrow * S_DIM + kn + vkc * 8, &vnxt[tid * 8]);
    }

    // mask words: 64 k-bits at q = q0 + qq*32 + j*16 + l15
    unsigned long long w64[2];
    {
      const unsigned long long* mw =
          bits + (size_t)kt * (B_DIM * S_DIM) + (size_t)b * S_DIM + q0 + qq * 32;
#pragma unroll
      for (int j = 0; j < 2; ++j) w64[j] = mw[j * 16 + l15];
    }

    // scores D[k][q]: wave = k rows [kw*16,+16) x q rows [qq*32,+32)
    s16x8 af[4];
#pragma unroll
    for (int kk = 0; kk < 4; ++kk) {
      int row = kw * 16 + l15;
      af[kk] = *(const s16x8*)&kcur[row * 128 + ((kk * 4 + quad) ^ (row & 7)) * 8];
    }
    f32x4 sacc[2] = {};
    __builtin_amdgcn_s_setprio(1);
#pragma unroll
    for (int kk = 0; kk < 4; ++kk)
#pragma unroll
      for (int j = 0; j < 2; ++j) sacc[j] = MFMA16(af[kk], qf[j][kk], sacc[j]);
    __builtin_amdgcn_s_setprio(0);

    // P = maskbit * relu(s) * scale/m -> packed bf16 -> LDS
#pragma unroll
    for (int j = 0; j < 2; ++j) {
      const unsigned int m4 = (unsigned int)(w64[j] >> (kw * 16 + quad * 4)) & 0xFu;
      float p[4];
#pragma unroll
      for (int r = 0; r < 4; ++r) {
        float t = fmaxf(sacc[j][r], 0.f) * invf[j];
        p[r] = ((m4 >> r) & 1u) ? t : 0.f;
      }
      unsigned int pk0, pk1;
      asm("v_cvt_pk_bf16_f32 %0, %1, %2" : "=v"(pk0) : "v"(p[0]), "v"(p[1]));
      asm("v_cvt_pk_bf16_f32 %0, %1, %2" : "=v"(pk1) : "v"(p[2]), "v"(p[3]));
      int q = qq * 32 + j * 16 + l15;
      int chunk = (kw * 2 + (quad >> 1)) ^ (q & 7);
      *(uint2*)&Ps[q * 64 + chunk * 8 + (quad & 1) * 4] = make_uint2(pk0, pk1);
    }

    // mid-iter barrier: lgkmcnt ONLY (P writes visible, kcur reads done);
    // prestage vm loads intentionally stay in flight across it
    asm volatile("s_waitcnt lgkmcnt(0)" ::: "memory");
    __builtin_amdgcn_sched_barrier(0);
    __builtin_amdgcn_s_barrier();
    __builtin_amdgcn_sched_barrier(0);

    // PV from V(kt): q rows [qq*32,+32) x c-cols [kw*32,+32)
#pragma unroll
    for (int ks = 0; ks < 2; ++ks) {
      s16x8 pf[2], vf[2];
#pragma unroll
      for (int i = 0; i < 2; ++i) {
        int row = qq * 32 + i * 16 + l15;
        pf[i] = *(const s16x8*)&Ps[row * 64 + ((ks * 4 + quad) ^ (row & 7)) * 8];
      }
#pragma unroll
      for (int j = 0; j < 2; ++j) {
        int row = kw * 32 + j * 16 + l15;
        vf[j] = *(const s16x8*)&vcur[row * 64 + ((ks * 4 + quad) ^ (row & 7)) * 8];
      }
      __builtin_amdgcn_s_setprio(1);
#pragma unroll
      for (int i = 0; i < 2; ++i)
#pragma unroll
        for (int j = 0; j < 2; ++j) pacc[i][j] = MFMA16(pf[i], vf[j], pacc[i][j]);
      __builtin_amdgcn_s_setprio(0);
    }
    __syncthreads();  // full drain: prestiges (issued at iter start) landed;
                      // Ps/vcur reads done before next iter's writes
  }

  // epilogue: CcT[b][q][h*128+c] bf16
  unsigned short* cb = CcT + (size_t)z * S_DIM * U_DIM;
#pragma unroll
  for (int i = 0; i < 2; ++i)
#pragma unroll
    for (int j = 0; j < 2; ++j) {
      f32x4 v = pacc[i][j];
#pragma unroll
      for (int r = 0; r < 4; ++r) {
        int q = q0 + qq * 32 + i * 16 + quad * 4 + r;
        int c = h * C_DIM + kw * 32 + j * 16 + l15;
        cb[(size_t)q * U_DIM + c] = f2bf(v[r]);
      }
    }
}

// ---------------------------------------------------------------------------
extern "C" void kernel_launch(void* const* d_in, const int* in_sizes, int n_in,
                              void* d_out, int out_size, void* d_ws, size_t ws_size,
                              hipStream_t stream) {
  const float* x = (const float*)d_in[0];
  const unsigned char* mask_raw = (const unsigned char*)d_in[1];
  const float* w_qkv = (const float*)d_in[2];
  const float* w_out = (const float*)d_in[3];
  float* out = (float*)d_out;

  char* ws = (char*)d_ws;
  int* flag = (int*)ws;                                  // 256 B
  float* invm = (float*)(ws + 256);                      // 64 KB
  unsigned long long* bits = (unsigned long long*)(ws + 256 + 65536);  // 2 MB
  unsigned short* wqkv_bf = (unsigned short*)((char*)bits + (size_t)B_DIM * S_DIM * 16 * 8);
  unsigned short* wout_bf = (unsigned short*)((char*)wqkv_bf + (size_t)3 * U_DIM * U_DIM * 2);
  char* heap = (char*)wout_bf + (size_t)U_DIM * U_DIM * 2;

  const size_t xT_pb = (size_t)U_DIM * S_DIM * 2;
  const size_t qkvT_pb = (size_t)3 * U_DIM * S_DIM * 2;
  const size_t vT_pb = (size_t)U_DIM * S_DIM * 2;
  const size_t ccT_pb = (size_t)U_DIM * S_DIM * 2;
  const size_t per_batch = xT_pb + qkvT_pb + vT_pb + ccT_pb;  // 12.58 MB
  const size_t fixed = (size_t)(heap - ws);
  int nb = (ws_size > fixed) ? (int)((ws_size - fixed) / per_batch) : 1;
  if (nb < 1) nb = 1;
  if (nb > B_DIM) nb = B_DIM;

  unsigned short* xT = (unsigned short*)heap;
  unsigned short* qkvT = (unsigned short*)(heap + (size_t)nb * xT_pb);
  unsigned short* VT = (unsigned short*)(heap + (size_t)nb * (xT_pb + qkvT_pb));
  unsigned short* CcT = (unsigned short*)(heap + (size_t)nb * (xT_pb + qkvT_pb + vT_pb));

  detect_mask<<<1, 256, 0, stream>>>(mask_raw, flag);
  pack_mask<<<dim3(S_DIM / 64, S_DIM / 64, B_DIM), 256, 0, stream>>>(mask_raw, flag, bits);
  invm_from_bits<<<(B_DIM * S_DIM) / 256, 256, 0, stream>>>(bits, invm);
  cvt_bf16<<<(3 * U_DIM * U_DIM) / 1024, 256, 0, stream>>>(w_qkv, wqkv_bf, 3 * U_DIM * U_DIM);
  cvt_bf16<<<(U_DIM * U_DIM) / 1024, 256, 0, stream>>>(w_out, wout_bf, U_DIM * U_DIM);

  for (int b0 = 0; b0 < B_DIM; b0 += nb) {
    int cnt = (B_DIM - b0 < nb) ? (B_DIM - b0) : nb;
    transpose_x<<<dim3(S_DIM / 32, U_DIM / 32, cnt), 256, 0, stream>>>(
        x + (size_t)b0 * U_DIM * S_DIM, xT);
    gemm256<unsigned short><<<dim3(3 * U_DIM / 256, S_DIM / 256, cnt), 512, 0, stream>>>(
        xT, wqkv_bf, qkvT, (long long)U_DIM * S_DIM, 0LL, (long long)3 * U_DIM * S_DIM, 3 * U_DIM);
    transpose_v<<<dim3(S_DIM / 32, U_DIM / 32, cnt), 256, 0, stream>>>(qkvT, VT);
    attn_mfma<<<dim3(S_DIM / 128, H_DIM, cnt), 1024, 0, stream>>>(
        qkvT, VT, bits, invm, CcT, b0);
    gemm256<float><<<dim3(S_DIM / 256, U_DIM / 256, cnt), 512, 0, stream>>>(
        wout_bf, CcT, out + (size_t)b0 * U_DIM * S_DIM, 0LL,
        (long long)U_DIM * S_DIM, (long long)U_DIM * S_DIM, S_DIM);
  }
}